// Round 1
// baseline (342.121 us; speedup 1.0000x reference)
//
#include <hip/hip_runtime.h>
#include <hip/hip_fp16.h>

#define NB  32
#define NLQ 128
#define NLK 4096
#define NDK 256
#define NDV 256

typedef _Float16 f16;
typedef _Float16 f16x4 __attribute__((ext_vector_type(4)));
typedef _Float16 f16x8 __attribute__((ext_vector_type(8)));
typedef float    f32x4 __attribute__((ext_vector_type(4)));

// Block: (batch b = blockIdx.y, query-tile qt = blockIdx.x) -> 16 queries.
// 8 waves/block; wave w owns keys [w*512, w*512+512), tiles of 16 keys.
// QK^T swapped (A=K tile, B=Q tile) so lane holds P[q=lane&15][k=(lane>>4)*4+j],
// which is exactly the A-fragment of mfma_f32_16x16x16f16 for PV.
__global__ __launch_bounds__(512, 2) void fvta_attn(
    const float* __restrict__ q_, const int* __restrict__ qlen_,
    const float* __restrict__ k_, const float* __restrict__ v_,
    const int* __restrict__ mask_, float* __restrict__ out_)
{
    __shared__ float accsum[16][NDV + 1];
    __shared__ float red_m[8][16];
    __shared__ float red_l[8][16];

    const int tid  = threadIdx.x;
    const int w    = tid >> 6;
    const int lane = tid & 63;
    const int l15  = lane & 15;
    const int lhi  = lane >> 4;      // 0..3
    const int b    = blockIdx.y;
    const int qt   = blockIdx.x;
    const int q0   = qt * 16;
    const int len  = qlen_[b];
    const float NEG_INF = -__builtin_inff();

    // zero the merge buffer (main loop never touches LDS)
    for (int i = tid; i < 16 * NDV; i += 512) accsum[i >> 8][i & 255] = 0.f;
    __syncthreads();

    // ---- Q fragments (B operand of QK): lane holds Q[q0+l15][kd*32 + lhi*8 + j]
    f16x8 qf[8];
    {
        const float* qrow = q_ + ((size_t)b * NLQ + (q0 + l15)) * NDK + lhi * 8;
        const bool qv = (q0 + l15) < len;   // invalid queries zeroed (ref semantics)
        #pragma unroll
        for (int kd = 0; kd < 8; ++kd) {
            f32x4 x = *(const f32x4*)(qrow + kd * 32);
            f32x4 y = *(const f32x4*)(qrow + kd * 32 + 4);
            f16x8 f;
            f[0] = (f16)x[0]; f[1] = (f16)x[1]; f[2] = (f16)x[2]; f[3] = (f16)x[3];
            f[4] = (f16)y[0]; f[5] = (f16)y[1]; f[6] = (f16)y[2]; f[7] = (f16)y[3];
            if (!qv) {
                #pragma unroll
                for (int c = 0; c < 8; ++c) f[c] = (f16)0.f;
            }
            qf[kd] = f;
        }
    }

    float m_run = NEG_INF, l_run = 0.f;
    f32x4 acc[16];   // lane holds acc[query=(lhi*4+j)][dv = d*16 + l15]
    #pragma unroll
    for (int i = 0; i < 16; ++i) acc[i] = (f32x4){0.f, 0.f, 0.f, 0.f};

    const float* kb = k_ + (size_t)b * NLK * NDK;
    const float* vb = v_ + (size_t)b * NLK * NDV;
    const int*   mb = mask_ + b * NLK;

    for (int t = 0; t < 32; ++t) {
        const int k0 = w * 512 + t * 16;

        // ---- QK^T: A = K tile (row=key=l15, k-dims lhi*8+j per 32-dim slice)
        f32x4 s4 = (f32x4){0.f, 0.f, 0.f, 0.f};
        {
            const float* krow = kb + (size_t)(k0 + l15) * NDK + lhi * 8;
            #pragma unroll
            for (int kd = 0; kd < 8; ++kd) {
                f32x4 x = *(const f32x4*)(krow + kd * 32);
                f32x4 y = *(const f32x4*)(krow + kd * 32 + 4);
                f16x8 kf;
                kf[0] = (f16)x[0]; kf[1] = (f16)x[1]; kf[2] = (f16)x[2]; kf[3] = (f16)x[3];
                kf[4] = (f16)y[0]; kf[5] = (f16)y[1]; kf[6] = (f16)y[2]; kf[7] = (f16)y[3];
                s4 = __builtin_amdgcn_mfma_f32_16x16x32_f16(kf, qf[kd], s4, 0, 0, 0);
            }
        }
        // s4[j] = score[key = k0 + lhi*4 + j][query = q0 + l15]

        // ---- mask -> -inf, online softmax (per query = l15; dups over lhi)
        const int mv = mb[k0 + l15];
        float s[4];
        #pragma unroll
        for (int j = 0; j < 4; ++j) {
            const int mk = __shfl(mv, lhi * 4 + j, 64);
            s[j] = mk ? NEG_INF : s4[j];
        }
        float tmax = fmaxf(fmaxf(s[0], s[1]), fmaxf(s[2], s[3]));
        tmax = fmaxf(tmax, __shfl_xor(tmax, 16, 64));
        tmax = fmaxf(tmax, __shfl_xor(tmax, 32, 64));
        const float mnew  = fmaxf(m_run, tmax);
        const bool  dead  = (mnew == NEG_INF);       // everything masked so far
        const float scale = dead ? 1.f : __expf(m_run - mnew);
        float p[4];
        #pragma unroll
        for (int j = 0; j < 4; ++j) p[j] = dead ? 0.f : __expf(s[j] - mnew);
        float ps = (p[0] + p[1]) + (p[2] + p[3]);
        ps += __shfl_xor(ps, 16, 64);
        ps += __shfl_xor(ps, 32, 64);
        l_run = l_run * scale + ps;
        m_run = mnew;

        // P fragment for PV (A operand): row=query=l15, k=key=lhi*4+j -> own p[j]
        f16x4 pa;
        pa[0] = (f16)p[0]; pa[1] = (f16)p[1]; pa[2] = (f16)p[2]; pa[3] = (f16)p[3];

        // rescale accumulators (scale indexed by query -> shuffle); skip if all 1
        if (!__all(scale == 1.f)) {
            float scj[4];
            #pragma unroll
            for (int j = 0; j < 4; ++j) scj[j] = __shfl(scale, lhi * 4 + j, 64);
            #pragma unroll
            for (int d = 0; d < 16; ++d) {
                acc[d][0] *= scj[0]; acc[d][1] *= scj[1];
                acc[d][2] *= scj[2]; acc[d][3] *= scj[3];
            }
        }

        // ---- PV: B frag = V[k0+lhi*4+j][d*16+l15], 64B-coalesced scalar loads
        {
            const float* vrow = vb + (size_t)(k0 + lhi * 4) * NDV + l15;
            #pragma unroll
            for (int d = 0; d < 16; ++d) {
                f16x4 vf;
                vf[0] = (f16)vrow[d * 16];
                vf[1] = (f16)vrow[1 * NDV + d * 16];
                vf[2] = (f16)vrow[2 * NDV + d * 16];
                vf[3] = (f16)vrow[3 * NDV + d * 16];
                acc[d] = __builtin_amdgcn_mfma_f32_16x16x16f16(pa, vf, acc[d], 0, 0, 0);
            }
        }
    }

    // ---- merge the 8 waves' online-softmax partials
    if (lane < 16) { red_m[w][lane] = m_run; red_l[w][lane] = l_run; }
    __syncthreads();

    #pragma unroll
    for (int j = 0; j < 4; ++j) {
        const int qj = lhi * 4 + j;
        float gm = red_m[0][qj];
        #pragma unroll
        for (int w2 = 1; w2 < 8; ++w2) gm = fmaxf(gm, red_m[w2][qj]);
        const float mw = __shfl(m_run, qj, 64);     // this wave's max for query qj
        const float fj = (mw == NEG_INF) ? 0.f : __expf(mw - gm);
        if (fj != 0.f) {
            #pragma unroll
            for (int d = 0; d < 16; ++d)
                atomicAdd(&accsum[qj][d * 16 + l15], acc[d][j] * fj);
        }
    }
    __syncthreads();

    // ---- finalize: divide by denom, mask invalid queries, mean over LQ, add to out
    if (tid < NDV) {
        const int dv = tid;
        float sum = 0.f;
        for (int qq = 0; qq < 16; ++qq) {
            if (q0 + qq >= len) continue;           // invalid query -> contributes 0
            float gm = red_m[0][qq];
            for (int w2 = 1; w2 < 8; ++w2) gm = fmaxf(gm, red_m[w2][qq]);
            if (gm == NEG_INF) continue;            // all keys masked -> NaN->0 in ref
            float gl = 0.f;
            for (int w2 = 0; w2 < 8; ++w2) {
                const float mw = red_m[w2][qq];
                if (mw != NEG_INF) gl += red_l[w2][qq] * __expf(mw - gm);
            }
            if (gl > 0.f) sum += accsum[qq][dv] / gl;
        }
        atomicAdd(&out_[b * NDV + dv], sum * (1.f / NLQ));
    }
}

extern "C" void kernel_launch(void* const* d_in, const int* in_sizes, int n_in,
                              void* d_out, int out_size, void* d_ws, size_t ws_size,
                              hipStream_t stream) {
    const float* q    = (const float*)d_in[0];
    const int*   qlen = (const int*)d_in[1];
    const float* k    = (const float*)d_in[2];
    const float* v    = (const float*)d_in[3];
    const int*   mask = (const int*)d_in[4];
    float* out = (float*)d_out;

    hipMemsetAsync(out, 0, (size_t)out_size * sizeof(float), stream);
    dim3 grid(NLQ / 16, NB);   // 8 q-tiles x 32 batches = 256 blocks
    fvta_attn<<<grid, dim3(512), 0, stream>>>(q, qlen, k, v, mask, out);
}

// Round 3
// 161.345 us; speedup vs baseline: 2.1204x; 2.1204x over previous
//
#include <hip/hip_runtime.h>
#include <hip/hip_fp16.h>
#include <stdint.h>

#define NB  32
#define NLQ 128
#define NLK 4096
#define NDK 256
#define NDV 256
#define KT  32

typedef _Float16 f16;
typedef _Float16 f16x4 __attribute__((ext_vector_type(4)));
typedef _Float16 f16x8 __attribute__((ext_vector_type(8)));
typedef float    f32x4 __attribute__((ext_vector_type(4)));

// ---------------- Kernel 1: per (key-split s, batch b) flash partials -------
// 8 waves x 16 queries = 128 queries per block; K/V staged f32->f16 in LDS.
// Both K and V tiles: [32 keys][256 dims] f16, element-swizzled
//   elem = row*256 + (col ^ ((row&15)<<3))   (bank-balanced b128 / u16 reads)
__global__ __launch_bounds__(512) void fvta_part1(
    const float* __restrict__ q_, const float* __restrict__ k_,
    const float* __restrict__ v_, const int* __restrict__ mask_,
    float* __restrict__ accw, float* __restrict__ mlw)
{
    __shared__ __align__(16) f16 KA[2][KT * NDK];
    __shared__ __align__(16) f16 VA[2][KT * NDV];

    const int tid = threadIdx.x, w = tid >> 6, lane = tid & 63;
    const int l15 = lane & 15, lhi = lane >> 4;
    const int s = blockIdx.x, b = blockIdx.y, S = gridDim.x;
    const int slice = NLK / S, nt = slice / KT, kbase = s * slice;
    const float NEG = -__builtin_inff();

    const float* kb = k_ + ((size_t)b * NLK + kbase) * NDK;
    const float* vb = v_ + ((size_t)b * NLK + kbase) * NDV;
    const int*   mb = mask_ + b * NLK + kbase;

    // ---- Q fragments: lane holds Q[w*16+l15][kd*32 + lhi*8 + 0..8)
    f16x8 qf[8];
    {
        const float* qrow = q_ + ((size_t)b * NLQ + w * 16 + l15) * NDK + lhi * 8;
        #pragma unroll
        for (int kd = 0; kd < 8; ++kd) {
            f32x4 x = *(const f32x4*)(qrow + kd * 32);
            f32x4 y = *(const f32x4*)(qrow + kd * 32 + 4);
            f16x8 f;
            f[0]=(f16)x[0]; f[1]=(f16)x[1]; f[2]=(f16)x[2]; f[3]=(f16)x[3];
            f[4]=(f16)y[0]; f[5]=(f16)y[1]; f[6]=(f16)y[2]; f[7]=(f16)y[3];
            qf[kd] = f;
        }
    }

    f32x4 accu[16];
    #pragma unroll
    for (int i = 0; i < 16; ++i) accu[i] = (f32x4){0.f, 0.f, 0.f, 0.f};
    float m_run = NEG, l_run = 0.f;

    f32x4 ks[4], vs[4];   // staged f32 for next tile (issue early, write late)

    // thread's staging coords: kk = r*8 + w (const per reg), d = lane*4
    auto stage = [&](f16* KAb, f16* VAb) {
        #pragma unroll
        for (int r = 0; r < 4; ++r) {
            const int kk = r * 8 + w;
            const int d  = lane * 4;
            const int e  = kk * NDK + (d ^ ((kk & 15) << 3));
            f32x4 x = ks[r];
            f16x4 hh; hh[0]=(f16)x[0]; hh[1]=(f16)x[1]; hh[2]=(f16)x[2]; hh[3]=(f16)x[3];
            *(f16x4*)(KAb + e) = hh;
            f32x4 y = vs[r];
            f16x4 gg; gg[0]=(f16)y[0]; gg[1]=(f16)y[1]; gg[2]=(f16)y[2]; gg[3]=(f16)y[3];
            *(f16x4*)(VAb + e) = gg;
        }
    };

    // prologue: load + stage tile 0
    #pragma unroll
    for (int r = 0; r < 4; ++r) {
        const int off = (r * 512 + tid) * 4;
        ks[r] = *(const f32x4*)(kb + off);
        vs[r] = *(const f32x4*)(vb + off);
    }
    stage(KA[0], VA[0]);
    __syncthreads();

    const int swz = l15 << 3;   // K read swizzle: row&15 == l15 for both halves

    for (int t = 0; t < nt; ++t) {
        const int cur = t & 1;
        if (t + 1 < nt) {   // prefetch next tile (stays in flight through compute)
            const float* ksrc = kb + (size_t)(t + 1) * KT * NDK;
            const float* vsrc = vb + (size_t)(t + 1) * KT * NDV;
            #pragma unroll
            for (int r = 0; r < 4; ++r) {
                const int off = (r * 512 + tid) * 4;
                ks[r] = *(const f32x4*)(ksrc + off);
                vs[r] = *(const f32x4*)(vsrc + off);
            }
        }
        const int k0 = t * KT;

        // ---- QK^T, both 16-key halves (A = K rows, B = Q)
        f32x4 s4a = (f32x4){0.f,0.f,0.f,0.f}, s4b = s4a;
        {
            const f16* k0p = &KA[cur][(0 * 16 + l15) * NDK];
            const f16* k1p = &KA[cur][(1 * 16 + l15) * NDK];
            #pragma unroll
            for (int kd = 0; kd < 8; ++kd) {
                const int col = (kd * 32 + lhi * 8) ^ swz;
                f16x8 kfa = *(const f16x8*)(k0p + col);
                s4a = __builtin_amdgcn_mfma_f32_16x16x32_f16(kfa, qf[kd], s4a, 0, 0, 0);
                f16x8 kfb = *(const f16x8*)(k1p + col);
                s4b = __builtin_amdgcn_mfma_f32_16x16x32_f16(kfb, qf[kd], s4b, 0, 0, 0);
            }
        }
        // s4a[j] = S[key=k0+lhi*4+j][q=l15], s4b[j] = S[key=k0+16+lhi*4+j][q=l15]

        // ---- mask -> -inf, online softmax over 32 keys
        const int4 m4a = *(const int4*)(mb + k0 + lhi * 4);
        const int4 m4b = *(const int4*)(mb + k0 + 16 + lhi * 4);
        float sa[4], sb[4];
        sa[0] = m4a.x ? NEG : s4a[0]; sa[1] = m4a.y ? NEG : s4a[1];
        sa[2] = m4a.z ? NEG : s4a[2]; sa[3] = m4a.w ? NEG : s4a[3];
        sb[0] = m4b.x ? NEG : s4b[0]; sb[1] = m4b.y ? NEG : s4b[1];
        sb[2] = m4b.z ? NEG : s4b[2]; sb[3] = m4b.w ? NEG : s4b[3];

        float tmax = fmaxf(fmaxf(fmaxf(sa[0], sa[1]), fmaxf(sa[2], sa[3])),
                           fmaxf(fmaxf(sb[0], sb[1]), fmaxf(sb[2], sb[3])));
        tmax = fmaxf(tmax, __shfl_xor(tmax, 16, 64));
        tmax = fmaxf(tmax, __shfl_xor(tmax, 32, 64));
        const float mnew = fmaxf(m_run, tmax);
        const bool  dead = (mnew == NEG);
        const float scale = dead ? 1.f : __expf(m_run - mnew);
        float pa4[4], pb4[4];
        #pragma unroll
        for (int j = 0; j < 4; ++j) {
            pa4[j] = dead ? 0.f : __expf(sa[j] - mnew);
            pb4[j] = dead ? 0.f : __expf(sb[j] - mnew);
        }
        float ps = (pa4[0] + pa4[1]) + (pa4[2] + pa4[3])
                 + (pb4[0] + pb4[1]) + (pb4[2] + pb4[3]);
        ps += __shfl_xor(ps, 16, 64);
        ps += __shfl_xor(ps, 32, 64);
        l_run = l_run * scale + ps;
        m_run = mnew;

        f16x4 pa, pb;
        pa[0]=(f16)pa4[0]; pa[1]=(f16)pa4[1]; pa[2]=(f16)pa4[2]; pa[3]=(f16)pa4[3];
        pb[0]=(f16)pb4[0]; pb[1]=(f16)pb4[1]; pb[2]=(f16)pb4[2]; pb[3]=(f16)pb4[3];

        if (!__all(scale == 1.f)) {
            float scj[4];
            #pragma unroll
            for (int j = 0; j < 4; ++j) scj[j] = __shfl(scale, lhi * 4 + j, 64);
            #pragma unroll
            for (int d = 0; d < 16; ++d) {
                accu[d][0] *= scj[0]; accu[d][1] *= scj[1];
                accu[d][2] *= scj[2]; accu[d][3] *= scj[3];
            }
        }

        // ---- PV: B frag = V[row=h*16+lhi*4+j][dv=d*16+l15] via swizzled u16 reads
        {
            const f16* VL = &VA[cur][0];
            #pragma unroll
            for (int h = 0; h < 2; ++h) {
                const f16x4 pfrag = h ? pb : pa;
                #pragma unroll
                for (int d = 0; d < 16; ++d) {
                    f16x4 vf;
                    #pragma unroll
                    for (int j = 0; j < 4; ++j) {
                        const int row = h * 16 + lhi * 4 + j;
                        const int col = (d * 16 + l15) ^ ((row & 15) << 3);
                        vf[j] = VL[row * NDV + col];
                    }
                    accu[d] = __builtin_amdgcn_mfma_f32_16x16x16f16(
                        pfrag, vf, accu[d], 0, 0, 0);
                }
            }
        }

        if (t + 1 < nt) stage(KA[cur ^ 1], VA[cur ^ 1]);
        __syncthreads();
    }

    // ---- write partials {acc, m, l} to workspace
    const size_t base = (size_t)(b * S + s) * NLQ + w * 16;
    #pragma unroll
    for (int j = 0; j < 4; ++j) {
        float* dst = accw + (base + lhi * 4 + j) * NDV + l15;
        #pragma unroll
        for (int d = 0; d < 16; ++d) dst[d * 16] = accu[d][j];
    }
    if (lane < 16) {
        mlw[(base + lane) * 2]     = m_run;
        mlw[(base + lane) * 2 + 1] = l_run;
    }
}

// ---------------- Kernel 2: merge key-splits, q-length mask, mean ----------
__global__ __launch_bounds__(256) void fvta_merge(
    const float* __restrict__ accw, const float* __restrict__ mlw,
    const int* __restrict__ qlen_, float* __restrict__ out_, int S)
{
    __shared__ float fac[16][9];
    const int qc = blockIdx.x, b = blockIdx.y, tid = threadIdx.x;
    const int len = qlen_[b];
    const float NEG = -__builtin_inff();

    if (tid < 16) {
        const int q = qc * 16 + tid;
        if (q < len) {
            float gm = NEG;
            for (int ss = 0; ss < S; ++ss)
                gm = fmaxf(gm, mlw[((size_t)(b * S + ss) * NLQ + q) * 2]);
            float L = 0.f;
            for (int ss = 0; ss < S; ++ss) {
                const float m = mlw[((size_t)(b * S + ss) * NLQ + q) * 2];
                const float l = mlw[((size_t)(b * S + ss) * NLQ + q) * 2 + 1];
                if (m != NEG) L += l * __expf(m - gm);
            }
            for (int ss = 0; ss < S; ++ss) {
                const float m = mlw[((size_t)(b * S + ss) * NLQ + q) * 2];
                fac[tid][ss] = (gm != NEG && L > 0.f && m != NEG)
                             ? __expf(m - gm) / L : 0.f;
            }
        } else {
            for (int ss = 0; ss < S; ++ss) fac[tid][ss] = 0.f;
        }
    }
    __syncthreads();

    float sum = 0.f;
    for (int qq = 0; qq < 16; ++qq) {
        const int q = qc * 16 + qq;
        for (int ss = 0; ss < S; ++ss) {
            const float f = fac[qq][ss];
            if (f != 0.f)
                sum += accw[((size_t)(b * S + ss) * NLQ + q) * NDV + tid] * f;
        }
    }
    atomicAdd(&out_[b * NDV + tid], sum * (1.f / NLQ));
}

extern "C" void kernel_launch(void* const* d_in, const int* in_sizes, int n_in,
                              void* d_out, int out_size, void* d_ws, size_t ws_size,
                              hipStream_t stream) {
    const float* q    = (const float*)d_in[0];
    const int*   qlen = (const int*)d_in[1];
    const float* k    = (const float*)d_in[2];
    const float* v    = (const float*)d_in[3];
    const int*   mask = (const int*)d_in[4];
    float* out = (float*)d_out;

    int S = 8;   // key splits; shrink if workspace is small (correct at any S)
    while (S > 1 && ((size_t)NB * S * NLQ * NDV * 4 + (size_t)NB * S * NLQ * 8) > ws_size)
        S >>= 1;
    float* accw = (float*)d_ws;
    float* mlw  = (float*)((char*)d_ws + (size_t)NB * S * NLQ * NDV * 4);

    hipMemsetAsync(out, 0, (size_t)out_size * sizeof(float), stream);
    dim3 g1(S, NB);
    fvta_part1<<<g1, 512, 0, stream>>>(q, k, v, mask, accw, mlw);
    dim3 g2(NLQ / 16, NB);
    fvta_merge<<<g2, 256, 0, stream>>>(accw, mlw, qlen, out, S);
}